// Round 2
// baseline (171.117 us; speedup 1.0000x reference)
//
#include <hip/hip_runtime.h>
#include <hip/hip_bf16.h>

// CfC / liquid-RNN scan on MFMA, R8: R7's register-resident math, split
// across 4 waves for 4x occupancy. R7 post-mortem: 1 wave/SIMD -> 58%+ stall
// (VALUBusy 30, Mfma 12, Occ 10) -- latency fully exposed. R8: each 16-pixel
// group's net is split: wave w owns backbone m-tile w (phase 1) and head
// tiles {2w,2w+1} (phase 2). R7's permutation algebra makes the exchange
// tiny and lane-aligned:
//   wave w's packed lecun acts  = 8B half of one A2 frag   (abuf, 8B/lane)
//   wave w's packed h pair      = dword w of every hpk[4]  (hbuf, 4B/lane)
// 2 barriers/step, 3KB LDS, conflict-free strides. 1024 blocks x 256 thr
// -> 4 blocks/CU, 4 waves/SIMD. Math is BITWISE identical to R7 (same MFMA
// operands/order, same bf16 quantization points) -> absmax must be exactly
// 0.009765625; any change flags a layout bug.

#define CIN      16
#define UNITS    32
#define BACKBONE 64
#define CZ       48
#define TSTEPS   32
#define HW       4096
#define NPIX     16
#define NTHREADS 256

typedef __attribute__((ext_vector_type(8))) short  short8;
typedef __attribute__((ext_vector_type(8))) __bf16 bf16x8;
typedef __attribute__((ext_vector_type(4))) float  float4v;
typedef __attribute__((ext_vector_type(4))) unsigned int uint4v;
typedef __attribute__((ext_vector_type(2))) unsigned int uint2v;

__device__ __forceinline__ unsigned short bf16_rne(float f) {
    unsigned u = __float_as_uint(f);
    return (unsigned short)((u + 0x7FFFu + ((u >> 16) & 1u)) >> 16);
}
__device__ __forceinline__ float bf16_tof(unsigned short h) {
    return __uint_as_float(((unsigned)h) << 16);
}
// packed f32x2 -> bf16x2 (RNE), single VALU op
__device__ __forceinline__ unsigned cvt_pk_bf16(float lo, float hi) {
    unsigned r;
    asm("v_cvt_pk_bf16_f32 %0, %1, %2" : "=v"(r) : "v"(lo), "v"(hi));
    return r;
}

#if __has_builtin(__builtin_amdgcn_exp2f)
#define EXP2F(x) __builtin_amdgcn_exp2f(x)
#else
#define EXP2F(x) __expf(0.69314718056f * (x))
#endif
#if __has_builtin(__builtin_amdgcn_rcpf)
#define RCPF(x) __builtin_amdgcn_rcpf(x)
#else
#define RCPF(x) __fdividef(1.0f, (x))
#endif

// 1.7159*tanh(0.666*v) = 1.7159 - 3.4318/(2^(1.332*log2e*v)+1)
__device__ __forceinline__ float lecun_tanh_f(float v) {
    float e = EXP2F(1.92166925f * v);
    return fmaf(-3.4318f, RCPF(e + 1.0f), 1.7159f);
}
__device__ __forceinline__ float tanh_f(float v) {
    float e = EXP2F(2.88539008f * v);
    return fmaf(-2.0f, RCPF(e + 1.0f), 1.0f);
}
__device__ __forceinline__ float sigmoid_f(float v) {
    float e = EXP2F(-1.44269504f * v);
    return RCPF(1.0f + e);
}
__device__ __forceinline__ float4v mfma16(bf16x8 a, bf16x8 b, float4v c) {
    return __builtin_amdgcn_mfma_f32_16x16x32_bf16(a, b, c, 0, 0, 0);
}
__device__ __forceinline__ void split8(const float* v, bf16x8& hi, bf16x8& lo) {
    short8 sh, sl;
    #pragma unroll
    for (int j = 0; j < 8; ++j) {
        unsigned short h = bf16_rne(v[j]);
        sh[j] = (short)h;
        sl[j] = (short)bf16_rne(v[j] - bf16_tof(h));
    }
    hi = __builtin_bit_cast(bf16x8, sh);
    lo = __builtin_bit_cast(bf16x8, sl);
}

__global__ __launch_bounds__(NTHREADS, 4)
void cfc_mfma_kernel(const float* __restrict__ x,   const float* __restrict__ Wb,
                     const float* __restrict__ bb,
                     const float* __restrict__ Wff1, const float* __restrict__ bff1,
                     const float* __restrict__ Wff2, const float* __restrict__ bff2,
                     const float* __restrict__ Wta,  const float* __restrict__ bta,
                     const float* __restrict__ Wtb,  const float* __restrict__ btb,
                     float* __restrict__ out)
{
    // exchange buffers: [wave][lane] -- stride-8B / stride-4B, conflict-free
    __shared__ unsigned abuf[4][64][2];   // packed lecun acts (A2 halves)
    __shared__ unsigned hbuf[4][64];      // packed h pairs (hpk dwords)

    const int tid  = threadIdx.x;
    const int w    = tid >> 6;          // wave id 0..3
    const int lane = tid & 63;
    const int ln   = lane & 15;         // MFMA m/n (pixel for B/C)
    const int lq   = lane >> 4;         // MFMA quad

    const int gpix = blockIdx.x * NPIX;
    const int b    = gpix >> 12;
    const int pinb = gpix & 4095;
    const int px   = pinb + ln;

    // ---- phase-1 A frags: backbone m-tile mt = w, hi+lo -------------------
    bf16x8 A1hi[2], A1lo[2];
    #pragma unroll
    for (int kt = 0; kt < 2; ++kt) {
        float v[8];
        #pragma unroll
        for (int j = 0; j < 8; ++j) {
            int c = kt * 32 + lq * 8 + j;
            v[j] = (c < CZ) ? Wb[(w * 16 + ln) * CZ + c] : 0.0f;
        }
        split8(v, A1hi[kt], A1lo[kt]);
    }
    float bbias[4];
    #pragma unroll
    for (int r = 0; r < 4; ++r) bbias[r] = bb[w * 16 + lq * 4 + r];

    // ---- phase-2 A frags: head tiles ti = 2w + i2, permuted rows/cols -----
    // row m=ln of tile ti -> unit (((ln>>2)+2)&3)*8 + ti, head ln&3
    // col k -> backbone neuron n = 32kt + (j>>2)*16 + lq*4 + (j&3)
    const int head = ln & 3;
    const float* Whp = (head == 0) ? Wff1 : (head == 1) ? Wff2 : (head == 2) ? Wta : Wtb;
    const int urow = (((ln >> 2) + 2) & 3) * 8;
    bf16x8 Ah_hi[2][2], Ah_lo[2][2];
    #pragma unroll
    for (int i2 = 0; i2 < 2; ++i2) {
        const int u = urow + 2 * w + i2;
        #pragma unroll
        for (int kt = 0; kt < 2; ++kt) {
            float v[8];
            #pragma unroll
            for (int j = 0; j < 8; ++j) {
                int n = 32 * kt + (j >> 2) * 16 + lq * 4 + (j & 3);
                v[j] = Whp[u * BACKBONE + n];
            }
            split8(v, Ah_hi[i2][kt], Ah_lo[i2][kt]);
        }
    }
    // gate-side units of THIS lane: ub + 2w + i2 (head = r in acc regs)
    const int ub = ((lq + 2) & 3) * 8;
    float hbias[2][4];
    #pragma unroll
    for (int i2 = 0; i2 < 2; ++i2) {
        int u2 = ub + 2 * w + i2;
        hbias[i2][0] = bff1[u2]; hbias[i2][1] = bff2[u2];
        hbias[i2][2] = bta[u2];  hbias[i2][3] = btb[u2];
    }

    // ---- per-lane global offsets ------------------------------------------
    const int cb = (lq & 1) * 8;        // lq2,3 mirror lq0,1 (L1-absorbed dup)
    unsigned xo[8], oo[2];
    #pragma unroll
    for (int j = 0; j < 8; ++j)
        xo[j] = (unsigned)(((b * CIN + cb + j) * TSTEPS) * HW + px);
    #pragma unroll
    for (int i2 = 0; i2 < 2; ++i2)
        oo[i2] = (unsigned)(((b * UNITS + ub + 2 * w + i2) * TSTEPS) * HW + px);

    // ---- prologue: h0 = 0 in hbuf, x_0 prefetch ---------------------------
    hbuf[w][lane] = 0u;
    float xa[8], xb2[8];
    #pragma unroll
    for (int j = 0; j < 8; ++j) xa[j] = x[xo[j]];
    unsigned toff = 0;
    __syncthreads();

    auto step = [&](int t, float (&xc)[8], float (&xn)[8]) {
        // prefetch x_{t+1} (dummy re-read at t=31)
        const unsigned tn = toff + ((t < TSTEPS - 1) ? (unsigned)HW : 0u);
        #pragma unroll
        for (int j = 0; j < 8; ++j) xn[j] = x[xo[j] + tn];

        // ---- gather h (step t-1 values, visible since barrier B) ----
        unsigned hpk[4];
        #pragma unroll
        for (int p = 0; p < 4; ++p) hpk[p] = hbuf[p][lane];

        // ---- build z fragments (replicated per wave, ~14 ops) ----
        unsigned xpk[4];
        #pragma unroll
        for (int p = 0; p < 4; ++p) xpk[p] = cvt_pk_bf16(xc[2 * p], xc[2 * p + 1]);
        const bool xl = (lq < 2);
        unsigned z0u[4], z1u[4];
        #pragma unroll
        for (int p = 0; p < 4; ++p) {
            z0u[p] = xl ? xpk[p] : hpk[p];
            z1u[p] = xl ? hpk[p] : 0u;   // lq2,3 kt1 = K-pad zeros
        }
        uint4v zv0 = {z0u[0], z0u[1], z0u[2], z0u[3]};
        uint4v zv1 = {z1u[0], z1u[1], z1u[2], z1u[3]};
        bf16x8 Z0 = __builtin_bit_cast(bf16x8, zv0);
        bf16x8 Z1 = __builtin_bit_cast(bf16x8, zv1);

        // ---- phase 1: this wave's backbone tile (4 MFMA) ----
        float4v a = {bbias[0], bbias[1], bbias[2], bbias[3]};
        a = mfma16(A1hi[0], Z0, a);
        a = mfma16(A1lo[0], Z0, a);
        a = mfma16(A1hi[1], Z1, a);
        a = mfma16(A1lo[1], Z1, a);

        // lecun_tanh + pack -> this wave's 8B half of A2; publish
        {
            float g0 = lecun_tanh_f(a[0]);
            float g1 = lecun_tanh_f(a[1]);
            float g2 = lecun_tanh_f(a[2]);
            float g3 = lecun_tanh_f(a[3]);
            uint2v d = {cvt_pk_bf16(g0, g1), cvt_pk_bf16(g2, g3)};
            *(uint2v*)&abuf[w][lane][0] = d;   // ds_write_b64, stride 8B
        }
        __syncthreads();   // barrier A: acts published

        // ---- assemble full A2 (2 frags) from 4 wave-halves ----
        uint2v a01 = *(const uint2v*)&abuf[0][lane][0];
        uint2v a23 = *(const uint2v*)&abuf[1][lane][0];
        uint2v a45 = *(const uint2v*)&abuf[2][lane][0];
        uint2v a67 = *(const uint2v*)&abuf[3][lane][0];
        uint4v w0 = {a01[0], a01[1], a23[0], a23[1]};
        uint4v w1 = {a45[0], a45[1], a67[0], a67[1]};
        bf16x8 A2[2] = {__builtin_bit_cast(bf16x8, w0), __builtin_bit_cast(bf16x8, w1)};

        // ---- phase 2: this wave's 2 head tiles, gate, store, publish h ----
        float hn[2];
        #pragma unroll
        for (int i2 = 0; i2 < 2; ++i2) {
            float4v c = {hbias[i2][0], hbias[i2][1], hbias[i2][2], hbias[i2][3]};
            c = mfma16(Ah_hi[i2][0], A2[0], c);
            c = mfma16(Ah_lo[i2][0], A2[0], c);
            c = mfma16(Ah_hi[i2][1], A2[1], c);
            c = mfma16(Ah_lo[i2][1], A2[1], c);
            float f1 = tanh_f(c[0]);
            float f2 = tanh_f(c[1]);
            float ti = sigmoid_f(c[2] + c[3]);
            float h  = fmaf(ti, f2 - f1, f1);
            out[oo[i2] + toff] = h;
            hn[i2] = h;
        }
        hbuf[w][lane] = cvt_pk_bf16(hn[0], hn[1]);   // hpk dword w
        __syncthreads();   // barrier B: h published for step t+1
        toff += (unsigned)HW;
    };

    #pragma unroll 1
    for (int t = 0; t < TSTEPS; t += 2) {
        step(t,     xa,  xb2);   // ping
        step(t + 1, xb2, xa);    // pong (static x double-buffer)
    }
}

extern "C" void kernel_launch(void* const* d_in, const int* in_sizes, int n_in,
                              void* d_out, int out_size, void* d_ws, size_t ws_size,
                              hipStream_t stream) {
    dim3 grid(4 * HW / NPIX);   // 1024 blocks x 4 waves -> 4 waves/SIMD
    cfc_mfma_kernel<<<grid, NTHREADS, 0, stream>>>(
        (const float*)d_in[0], (const float*)d_in[1], (const float*)d_in[2],
        (const float*)d_in[3], (const float*)d_in[4], (const float*)d_in[5],
        (const float*)d_in[6], (const float*)d_in[7], (const float*)d_in[8],
        (const float*)d_in[9], (const float*)d_in[10],
        (float*)d_out);
}

// Round 3
// 160.172 us; speedup vs baseline: 1.0683x; 1.0683x over previous
//
#include <hip/hip_runtime.h>
#include <hip/hip_bf16.h>

// CfC / liquid-RNN scan on MFMA, R9 = R8 + non-draining barriers.
// R8 post-mortem: occupancy 10->38% yet time identical to R7 (83us) -- not
// occupancy-bound. Culprit (guide Sec5 m97): __syncthreads() compiles to
// s_waitcnt vmcnt(0) expcnt(0) lgkmcnt(0) + s_barrier. With 2 barriers/step
// that puts the FULL x-prefetch HBM latency (~900cy) and the out-store ack
// on every step's critical path -- the prefetch never overlapped anything.
// R9: raw `s_waitcnt lgkmcnt(0); s_barrier` via asm volatile (+"memory"
// clobber = compiler fence for the LDS publish/consume pairs). vmcnt is
// NEVER drained in the loop (T4): x loads float across barriers with a full
// step of slack; stores are fire-and-forget. Math bitwise-identical to
// R7/R8 -> absmax must be exactly 0.009765625 (layout-bug tripwire).

#define CIN      16
#define UNITS    32
#define BACKBONE 64
#define CZ       48
#define TSTEPS   32
#define HW       4096
#define NPIX     16
#define NTHREADS 256

typedef __attribute__((ext_vector_type(8))) short  short8;
typedef __attribute__((ext_vector_type(8))) __bf16 bf16x8;
typedef __attribute__((ext_vector_type(4))) float  float4v;
typedef __attribute__((ext_vector_type(4))) unsigned int uint4v;
typedef __attribute__((ext_vector_type(2))) unsigned int uint2v;

// LDS-only barrier: drain LDS pipe (publish visible), sync waves, but leave
// vmem (x prefetch, out stores) in flight. "memory" = compiler-level fence.
#define BAR_LDS() asm volatile("s_waitcnt lgkmcnt(0)\n\ts_barrier" ::: "memory")

__device__ __forceinline__ unsigned short bf16_rne(float f) {
    unsigned u = __float_as_uint(f);
    return (unsigned short)((u + 0x7FFFu + ((u >> 16) & 1u)) >> 16);
}
__device__ __forceinline__ float bf16_tof(unsigned short h) {
    return __uint_as_float(((unsigned)h) << 16);
}
// packed f32x2 -> bf16x2 (RNE), single VALU op
__device__ __forceinline__ unsigned cvt_pk_bf16(float lo, float hi) {
    unsigned r;
    asm("v_cvt_pk_bf16_f32 %0, %1, %2" : "=v"(r) : "v"(lo), "v"(hi));
    return r;
}

#if __has_builtin(__builtin_amdgcn_exp2f)
#define EXP2F(x) __builtin_amdgcn_exp2f(x)
#else
#define EXP2F(x) __expf(0.69314718056f * (x))
#endif
#if __has_builtin(__builtin_amdgcn_rcpf)
#define RCPF(x) __builtin_amdgcn_rcpf(x)
#else
#define RCPF(x) __fdividef(1.0f, (x))
#endif

// 1.7159*tanh(0.666*v) = 1.7159 - 3.4318/(2^(1.332*log2e*v)+1)
__device__ __forceinline__ float lecun_tanh_f(float v) {
    float e = EXP2F(1.92166925f * v);
    return fmaf(-3.4318f, RCPF(e + 1.0f), 1.7159f);
}
__device__ __forceinline__ float tanh_f(float v) {
    float e = EXP2F(2.88539008f * v);
    return fmaf(-2.0f, RCPF(e + 1.0f), 1.0f);
}
__device__ __forceinline__ float sigmoid_f(float v) {
    float e = EXP2F(-1.44269504f * v);
    return RCPF(1.0f + e);
}
__device__ __forceinline__ float4v mfma16(bf16x8 a, bf16x8 b, float4v c) {
    return __builtin_amdgcn_mfma_f32_16x16x32_bf16(a, b, c, 0, 0, 0);
}
__device__ __forceinline__ void split8(const float* v, bf16x8& hi, bf16x8& lo) {
    short8 sh, sl;
    #pragma unroll
    for (int j = 0; j < 8; ++j) {
        unsigned short h = bf16_rne(v[j]);
        sh[j] = (short)h;
        sl[j] = (short)bf16_rne(v[j] - bf16_tof(h));
    }
    hi = __builtin_bit_cast(bf16x8, sh);
    lo = __builtin_bit_cast(bf16x8, sl);
}

__global__ __launch_bounds__(NTHREADS, 4)
void cfc_mfma_kernel(const float* __restrict__ x,   const float* __restrict__ Wb,
                     const float* __restrict__ bb,
                     const float* __restrict__ Wff1, const float* __restrict__ bff1,
                     const float* __restrict__ Wff2, const float* __restrict__ bff2,
                     const float* __restrict__ Wta,  const float* __restrict__ bta,
                     const float* __restrict__ Wtb,  const float* __restrict__ btb,
                     float* __restrict__ out)
{
    // exchange buffers: [wave][lane] -- stride-8B / stride-4B, conflict-free
    __shared__ unsigned abuf[4][64][2];   // packed lecun acts (A2 halves)
    __shared__ unsigned hbuf[4][64];      // packed h pairs (hpk dwords)

    const int tid  = threadIdx.x;
    const int w    = tid >> 6;          // wave id 0..3
    const int lane = tid & 63;
    const int ln   = lane & 15;         // MFMA m/n (pixel for B/C)
    const int lq   = lane >> 4;         // MFMA quad

    const int gpix = blockIdx.x * NPIX;
    const int b    = gpix >> 12;
    const int pinb = gpix & 4095;
    const int px   = pinb + ln;

    // ---- phase-1 A frags: backbone m-tile mt = w, hi+lo -------------------
    bf16x8 A1hi[2], A1lo[2];
    #pragma unroll
    for (int kt = 0; kt < 2; ++kt) {
        float v[8];
        #pragma unroll
        for (int j = 0; j < 8; ++j) {
            int c = kt * 32 + lq * 8 + j;
            v[j] = (c < CZ) ? Wb[(w * 16 + ln) * CZ + c] : 0.0f;
        }
        split8(v, A1hi[kt], A1lo[kt]);
    }
    float bbias[4];
    #pragma unroll
    for (int r = 0; r < 4; ++r) bbias[r] = bb[w * 16 + lq * 4 + r];

    // ---- phase-2 A frags: head tiles ti = 2w + i2, permuted rows/cols -----
    // row m=ln of tile ti -> unit (((ln>>2)+2)&3)*8 + ti, head ln&3
    // col k -> backbone neuron n = 32kt + (j>>2)*16 + lq*4 + (j&3)
    const int head = ln & 3;
    const float* Whp = (head == 0) ? Wff1 : (head == 1) ? Wff2 : (head == 2) ? Wta : Wtb;
    const int urow = (((ln >> 2) + 2) & 3) * 8;
    bf16x8 Ah_hi[2][2], Ah_lo[2][2];
    #pragma unroll
    for (int i2 = 0; i2 < 2; ++i2) {
        const int u = urow + 2 * w + i2;
        #pragma unroll
        for (int kt = 0; kt < 2; ++kt) {
            float v[8];
            #pragma unroll
            for (int j = 0; j < 8; ++j) {
                int n = 32 * kt + (j >> 2) * 16 + lq * 4 + (j & 3);
                v[j] = Whp[u * BACKBONE + n];
            }
            split8(v, Ah_hi[i2][kt], Ah_lo[i2][kt]);
        }
    }
    // gate-side units of THIS lane: ub + 2w + i2 (head = r in acc regs)
    const int ub = ((lq + 2) & 3) * 8;
    float hbias[2][4];
    #pragma unroll
    for (int i2 = 0; i2 < 2; ++i2) {
        int u2 = ub + 2 * w + i2;
        hbias[i2][0] = bff1[u2]; hbias[i2][1] = bff2[u2];
        hbias[i2][2] = bta[u2];  hbias[i2][3] = btb[u2];
    }

    // ---- per-lane global offsets ------------------------------------------
    const int cb = (lq & 1) * 8;        // lq2,3 mirror lq0,1 (L1-absorbed dup)
    unsigned xo[8], oo[2];
    #pragma unroll
    for (int j = 0; j < 8; ++j)
        xo[j] = (unsigned)(((b * CIN + cb + j) * TSTEPS) * HW + px);
    #pragma unroll
    for (int i2 = 0; i2 < 2; ++i2)
        oo[i2] = (unsigned)(((b * UNITS + ub + 2 * w + i2) * TSTEPS) * HW + px);

    // ---- prologue: h0 = 0 in hbuf, x_0 prefetch ---------------------------
    hbuf[w][lane] = 0u;
    float xa[8], xb2[8];
    #pragma unroll
    for (int j = 0; j < 8; ++j) xa[j] = x[xo[j]];
    unsigned toff = 0;
    BAR_LDS();

    auto step = [&](int t, float (&xc)[8], float (&xn)[8]) {
        // prefetch x_{t+1} (dummy re-read at t=31); stays in flight across
        // both barriers -- consumed only at the top of step t+1.
        const unsigned tn = toff + ((t < TSTEPS - 1) ? (unsigned)HW : 0u);
        #pragma unroll
        for (int j = 0; j < 8; ++j) xn[j] = x[xo[j] + tn];

        // ---- gather h (step t-1 values, visible since barrier B) ----
        unsigned hpk[4];
        #pragma unroll
        for (int p = 0; p < 4; ++p) hpk[p] = hbuf[p][lane];

        // ---- build z fragments (replicated per wave, ~14 ops) ----
        unsigned xpk[4];
        #pragma unroll
        for (int p = 0; p < 4; ++p) xpk[p] = cvt_pk_bf16(xc[2 * p], xc[2 * p + 1]);
        const bool xl = (lq < 2);
        unsigned z0u[4], z1u[4];
        #pragma unroll
        for (int p = 0; p < 4; ++p) {
            z0u[p] = xl ? xpk[p] : hpk[p];
            z1u[p] = xl ? hpk[p] : 0u;   // lq2,3 kt1 = K-pad zeros
        }
        uint4v zv0 = {z0u[0], z0u[1], z0u[2], z0u[3]};
        uint4v zv1 = {z1u[0], z1u[1], z1u[2], z1u[3]};
        bf16x8 Z0 = __builtin_bit_cast(bf16x8, zv0);
        bf16x8 Z1 = __builtin_bit_cast(bf16x8, zv1);

        // ---- phase 1: this wave's backbone tile (4 MFMA) ----
        float4v a = {bbias[0], bbias[1], bbias[2], bbias[3]};
        a = mfma16(A1hi[0], Z0, a);
        a = mfma16(A1lo[0], Z0, a);
        a = mfma16(A1hi[1], Z1, a);
        a = mfma16(A1lo[1], Z1, a);

        // lecun_tanh + pack -> this wave's 8B half of A2; publish
        {
            float g0 = lecun_tanh_f(a[0]);
            float g1 = lecun_tanh_f(a[1]);
            float g2 = lecun_tanh_f(a[2]);
            float g3 = lecun_tanh_f(a[3]);
            uint2v d = {cvt_pk_bf16(g0, g1), cvt_pk_bf16(g2, g3)};
            *(uint2v*)&abuf[w][lane][0] = d;   // ds_write_b64, stride 8B
        }
        BAR_LDS();   // barrier A: acts published (LDS drained, vmem in flight)

        // ---- assemble full A2 (2 frags) from 4 wave-halves ----
        uint2v a01 = *(const uint2v*)&abuf[0][lane][0];
        uint2v a23 = *(const uint2v*)&abuf[1][lane][0];
        uint2v a45 = *(const uint2v*)&abuf[2][lane][0];
        uint2v a67 = *(const uint2v*)&abuf[3][lane][0];
        uint4v w0 = {a01[0], a01[1], a23[0], a23[1]};
        uint4v w1 = {a45[0], a45[1], a67[0], a67[1]};
        bf16x8 A2[2] = {__builtin_bit_cast(bf16x8, w0), __builtin_bit_cast(bf16x8, w1)};

        // ---- phase 2: this wave's 2 head tiles, gate, store, publish h ----
        float hn[2];
        #pragma unroll
        for (int i2 = 0; i2 < 2; ++i2) {
            float4v c = {hbias[i2][0], hbias[i2][1], hbias[i2][2], hbias[i2][3]};
            c = mfma16(Ah_hi[i2][0], A2[0], c);
            c = mfma16(Ah_lo[i2][0], A2[0], c);
            c = mfma16(Ah_hi[i2][1], A2[1], c);
            c = mfma16(Ah_lo[i2][1], A2[1], c);
            float f1 = tanh_f(c[0]);
            float f2 = tanh_f(c[1]);
            float ti = sigmoid_f(c[2] + c[3]);
            float h  = fmaf(ti, f2 - f1, f1);
            out[oo[i2] + toff] = h;    // async store; never drained in loop
            hn[i2] = h;
        }
        hbuf[w][lane] = cvt_pk_bf16(hn[0], hn[1]);   // hpk dword w
        BAR_LDS();   // barrier B: h published for step t+1
        toff += (unsigned)HW;
    };

    #pragma unroll 1
    for (int t = 0; t < TSTEPS; t += 2) {
        step(t,     xa,  xb2);   // ping
        step(t + 1, xb2, xa);    // pong (static x double-buffer)
    }
}

extern "C" void kernel_launch(void* const* d_in, const int* in_sizes, int n_in,
                              void* d_out, int out_size, void* d_ws, size_t ws_size,
                              hipStream_t stream) {
    dim3 grid(4 * HW / NPIX);   // 1024 blocks x 4 waves -> 4 waves/SIMD
    cfc_mfma_kernel<<<grid, NTHREADS, 0, stream>>>(
        (const float*)d_in[0], (const float*)d_in[1], (const float*)d_in[2],
        (const float*)d_in[3], (const float*)d_in[4], (const float*)d_in[5],
        (const float*)d_in[6], (const float*)d_in[7], (const float*)d_in[8],
        (const float*)d_in[9], (const float*)d_in[10],
        (float*)d_out);
}